// Round 8
// baseline (84.050 us; speedup 1.0000x reference)
//
#include <hip/hip_runtime.h>
#include <math.h>

#define BATCH     128
#define N_NODES   32768
#define N_CHILD   65536
#define NNZ_TOTAL 1048576
#define LOG2E     1.44269504f

typedef __attribute__((ext_vector_type(2))) float fx2;

// ---------------------------------------------------------------------------
// Kernel A: fp8 exp table, per-column power-of-2 scale, register-resident.
//   thread t: column cl = t&63, batch quarter q = t>>6 (32 values, registers)
//   col max via 4-way LDS reduce; e = exp2(fma(ll, log2e, k)) in [.., 256)
// ---------------------------------------------------------------------------
__global__ __launch_bounds__(256) void exp8_kernel(
    const float* __restrict__ child_ll, unsigned char* __restrict__ ex8,
    float* __restrict__ winv) {
    const int c0 = blockIdx.x * 64;
    const int t  = threadIdx.x;
    const int cl = t & 63;
    const int q  = t >> 6;                 // batch quarter [q*32, q*32+32)

    float v[32];
    float m = -3.4e38f;
    const float* bp = child_ll + (size_t)(q * 32) * N_CHILD + c0 + cl;
#pragma unroll
    for (int j = 0; j < 32; ++j) {         // coalesced: 64 lanes consecutive c
        v[j] = bp[(size_t)j * N_CHILD];
        m = fmaxf(m, v[j]);
    }

    __shared__ float smx[4][64];
    __shared__ float skf[64];
    smx[q][cl] = m;
    __syncthreads();
    if (t < 64) {
        const float mm = fmaxf(fmaxf(smx[0][t], smx[1][t]),
                               fmaxf(smx[2][t], smx[3][t]));
        const int ks = 7 - (int)floorf(mm * LOG2E);   // colmax*2^ks in [128,256)
        skf[t] = (float)ks;
        winv[c0 + t] = exp2f((float)(-ks));
    }
    __syncthreads();
    const float kf = skf[cl];

    unsigned ow[8];
#pragma unroll
    for (int p = 0; p < 8; ++p) {
        const float a0 = exp2f(fmaf(v[4 * p + 0], LOG2E, kf));
        const float a1 = exp2f(fmaf(v[4 * p + 1], LOG2E, kf));
        const float a2 = exp2f(fmaf(v[4 * p + 2], LOG2E, kf));
        const float a3 = exp2f(fmaf(v[4 * p + 3], LOG2E, kf));
        unsigned u = 0;
        u = __builtin_amdgcn_cvt_pk_fp8_f32(a0, a1, u, false);
        u = __builtin_amdgcn_cvt_pk_fp8_f32(a2, a3, u, true);
        ow[p] = u;
    }

    __shared__ unsigned char sby[64 * 144];   // byte rows, stride 144 (16-mult)
    *(uint4*)&sby[cl * 144 + q * 32]      = *(uint4*)&ow[0];
    *(uint4*)&sby[cl * 144 + q * 32 + 16] = *(uint4*)&ow[4];
    __syncthreads();

    const int sub = t & 7, cc = t >> 3;
#pragma unroll
    for (int p = 0; p < 2; ++p) {             // store: contiguous 1KB per wave
        const int c = cc + p * 32;
        *(uint4*)&ex8[(size_t)(c0 + c) * 128 + sub * 16] =
            *(const uint4*)&sby[c * 144 + sub * 16];
    }
}

// ---------------------------------------------------------------------------
// Kernel B (fused prep):
//  blocks [0,1024):       wfold[i] = exp(log_w[i]) * winv[cols[i]]
//  blocks [1024,3072):    per row r (16 lanes): binary-search start/end,
//                         logzv[r] = log(sum exp(log_w[seg])), row_start[r]
// ---------------------------------------------------------------------------
__global__ __launch_bounds__(256) void prep_kernel(
    const float* __restrict__ log_w, const int* __restrict__ cols,
    const float* __restrict__ winv, const int* __restrict__ rows,
    float* __restrict__ wfold, int* __restrict__ row_start,
    float* __restrict__ logzv) {
    const int bid = blockIdx.x;
    const int t   = threadIdx.x;
    if (bid < 1024) {
        const int i = (bid * 256 + t) * 4;
        const float4 lw = *(const float4*)&log_w[i];
        const int4   cc = *(const int4*)&cols[i];
        float4 o;
        o.x = expf(lw.x) * winv[cc.x];
        o.y = expf(lw.y) * winv[cc.y];
        o.z = expf(lw.z) * winv[cc.z];
        o.w = expf(lw.w) * winv[cc.w];
        *(float4*)&wfold[i] = o;
        if (bid == 0 && t == 0) row_start[N_NODES] = NNZ_TOTAL;
    } else {
        const int wave = t >> 6, lane = t & 63;
        const int grp = lane >> 4, j = lane & 15;
        const int r = (bid - 1024) * 16 + wave * 4 + grp;
        int lo = 0, hi = NNZ_TOTAL;
        while (lo < hi) {
            const int mid = (lo + hi) >> 1;
            if (rows[mid] < r) lo = mid + 1; else hi = mid;
        }
        const int s = lo;
        int lo2 = s, hi2 = NNZ_TOTAL;
        while (lo2 < hi2) {
            const int mid = (lo2 + hi2) >> 1;
            if (rows[mid] < r + 1) lo2 = mid + 1; else hi2 = mid;
        }
        const int e = lo2;
        float sum = 0.f;
        for (int i = s + j; i < e; i += 16) sum += expf(log_w[i]);
        sum += __shfl_xor(sum, 1, 64);
        sum += __shfl_xor(sum, 2, 64);
        sum += __shfl_xor(sum, 4, 64);
        sum += __shfl_xor(sum, 8, 64);
        if (j == 0) { row_start[r] = s; logzv[r] = logf(sum); }
    }
}

// ---------------------------------------------------------------------------
// Kernel C: per-row sum, one wave per row. No LDS crossbar in the loop:
// granule meta (cols/wfold) via broadcast VMEM loads; 8 dwordx4 gathers
// (8 nnz each) in flight; epilogue = one LDS stage + float2 reads.
// ---------------------------------------------------------------------------
__global__ __launch_bounds__(256, 4) void sum_rows_kernel(
    const unsigned char* __restrict__ ex8, const float* __restrict__ wfold,
    const int* __restrict__ cols, const int* __restrict__ row_start,
    const float* __restrict__ logzv, float* __restrict__ out) {
    const int wave = threadIdx.x >> 6;   // 0..3
    const int lane = threadIdx.x & 63;
    const int bid  = blockIdx.x;         // grid = 8192
    const int rb   = (bid & 7) * (N_NODES / 4 / 8) + (bid >> 3);
    const int r    = rb * 4 + wave;

    const int start = row_start[r];
    const int end   = row_start[r + 1];
    const int slot  = lane >> 3;                 // nnz slot within granule
    const int sub   = lane & 7;                  // 16B chunk within 128B row
    const unsigned boff = (unsigned)sub * 16u;

    float acc[16];
#pragma unroll
    for (int k = 0; k < 16; ++k) acc[k] = 0.f;

    for (int base = start; base < end; base += 64) {
        const int seg = end - base;              // wave-uniform
        int   ct[8];
        float wt[8];
        uint4 g[8];

        // Phase A: granule meta (8 lanes share each address -> broadcast)
#pragma unroll
        for (int t8 = 0; t8 < 8; ++t8) {
            if (t8 * 8 < seg) {
                const int i = base + t8 * 8 + slot;
                ct[t8] = cols[min(i, NNZ_TOTAL - 1)];
                wt[t8] = (i < end) ? wfold[i] : 0.f;
            }
        }
        // Phase B: issue all gathers
#pragma unroll
        for (int t8 = 0; t8 < 8; ++t8) {
            if (t8 * 8 < seg)
                g[t8] = *(const uint4*)(ex8 +
                        ((size_t)(unsigned)ct[t8] << 7) + boff);
        }
        // Phase C: consume (fp8 -> f32 packed cvt)
#pragma unroll
        for (int t8 = 0; t8 < 8; ++t8) {
            if (t8 * 8 < seg) {
                const float wtv = wt[t8];
                const unsigned* gu = (const unsigned*)&g[t8];
#pragma unroll
                for (int q = 0; q < 4; ++q) {
                    const fx2 lo = __builtin_amdgcn_cvt_pk_f32_fp8((int)gu[q], false);
                    const fx2 hi = __builtin_amdgcn_cvt_pk_f32_fp8((int)gu[q], true);
                    acc[q * 4 + 0] = fmaf(wtv, lo.x, acc[q * 4 + 0]);
                    acc[q * 4 + 1] = fmaf(wtv, lo.y, acc[q * 4 + 1]);
                    acc[q * 4 + 2] = fmaf(wtv, hi.x, acc[q * 4 + 2]);
                    acc[q * 4 + 3] = fmaf(wtv, hi.y, acc[q * 4 + 3]);
                }
            }
        }
    }

    // epilogue: stage partials, reduce over the 8 slots
    __shared__ float red[4][8][132];   // [wave][slot][batch 0..127 +pad]
#pragma unroll
    for (int u = 0; u < 4; ++u) {
        const float4 vv = {acc[4 * u], acc[4 * u + 1],
                           acc[4 * u + 2], acc[4 * u + 3]};
        *(float4*)&red[wave][slot][sub * 16 + 4 * u] = vv;
    }
    __syncthreads();

    const int b0 = lane * 2;
    float s0 = 0.f, s1 = 0.f;
#pragma unroll
    for (int sl = 0; sl < 8; ++sl) {
        const float2 p = *(const float2*)&red[wave][sl][b0];
        s0 += p.x;
        s1 += p.y;
    }
    const float lz = logzv[r];
    out[(size_t)b0 * N_NODES + r]       = logf(s0) - lz;
    out[(size_t)(b0 + 1) * N_NODES + r] = logf(s1) - lz;
}

// ---------------------------------------------------------------------------
extern "C" void kernel_launch(void* const* d_in, const int* in_sizes, int n_in,
                              void* d_out, int out_size, void* d_ws, size_t ws_size,
                              hipStream_t stream) {
    const float* child_ll = (const float*)d_in[0];
    const float* log_w    = (const float*)d_in[1];
    const int*   rows     = (const int*)d_in[2];
    const int*   cols     = (const int*)d_in[3];
    float*       out      = (float*)d_out;

    // workspace layout
    unsigned char* ex8 = (unsigned char*)d_ws;                             // 8.4 MB
    float* winv      = (float*)((char*)d_ws + (size_t)N_CHILD * 128);      // 256 KB
    float* wfold     = (float*)((char*)winv + (size_t)N_CHILD * 4);        // 4 MB
    int*   row_start = (int*)((char*)wfold + (size_t)NNZ_TOTAL * 4);       // 128 KB
    float* logzv     = (float*)((char*)row_start + (size_t)(N_NODES + 1) * 4);

    exp8_kernel<<<N_CHILD / 64, 256, 0, stream>>>(child_ll, ex8, winv);
    prep_kernel<<<3072, 256, 0, stream>>>(log_w, cols, winv, rows,
                                          wfold, row_start, logzv);
    sum_rows_kernel<<<N_NODES / 4, 256, 0, stream>>>(ex8, wfold, cols,
                                                     row_start, logzv, out);
}

// Round 9
// 72.277 us; speedup vs baseline: 1.1629x; 1.1629x over previous
//
#include <hip/hip_runtime.h>
#include <math.h>

#define BATCH     128
#define N_NODES   32768
#define N_CHILD   65536
#define NNZ_TOTAL 1048576
#define LOG2E     1.44269504f

typedef __attribute__((ext_vector_type(2))) float fx2;

// ---------------------------------------------------------------------------
// Kernel A: fp8 exp table, per-column power-of-2 scale, register-resident.
// ---------------------------------------------------------------------------
__global__ __launch_bounds__(256) void exp8_kernel(
    const float* __restrict__ child_ll, unsigned char* __restrict__ ex8,
    float* __restrict__ winv) {
    const int c0 = blockIdx.x * 64;
    const int t  = threadIdx.x;
    const int cl = t & 63;
    const int q  = t >> 6;                 // batch quarter [q*32, q*32+32)

    float v[32];
    float m = -3.4e38f;
    const float* bp = child_ll + (size_t)(q * 32) * N_CHILD + c0 + cl;
#pragma unroll
    for (int j = 0; j < 32; ++j) {
        v[j] = bp[(size_t)j * N_CHILD];
        m = fmaxf(m, v[j]);
    }

    __shared__ float smx[4][64];
    __shared__ float skf[64];
    smx[q][cl] = m;
    __syncthreads();
    if (t < 64) {
        const float mm = fmaxf(fmaxf(smx[0][t], smx[1][t]),
                               fmaxf(smx[2][t], smx[3][t]));
        const int ks = 7 - (int)floorf(mm * LOG2E);   // colmax*2^ks in [128,256)
        skf[t] = (float)ks;
        winv[c0 + t] = exp2f((float)(-ks));
    }
    __syncthreads();
    const float kf = skf[cl];

    unsigned ow[8];
#pragma unroll
    for (int p = 0; p < 8; ++p) {
        const float a0 = exp2f(fmaf(v[4 * p + 0], LOG2E, kf));
        const float a1 = exp2f(fmaf(v[4 * p + 1], LOG2E, kf));
        const float a2 = exp2f(fmaf(v[4 * p + 2], LOG2E, kf));
        const float a3 = exp2f(fmaf(v[4 * p + 3], LOG2E, kf));
        unsigned u = 0;
        u = __builtin_amdgcn_cvt_pk_fp8_f32(a0, a1, u, false);
        u = __builtin_amdgcn_cvt_pk_fp8_f32(a2, a3, u, true);
        ow[p] = u;
    }

    __shared__ unsigned char sby[64 * 144];
    *(uint4*)&sby[cl * 144 + q * 32]      = *(uint4*)&ow[0];
    *(uint4*)&sby[cl * 144 + q * 32 + 16] = *(uint4*)&ow[4];
    __syncthreads();

    const int sub = t & 7, cc = t >> 3;
#pragma unroll
    for (int p = 0; p < 2; ++p) {
        const int c = cc + p * 32;
        *(uint4*)&ex8[(size_t)(c0 + c) * 128 + sub * 16] =
            *(const uint4*)&sby[c * 144 + sub * 16];
    }
}

// ---------------------------------------------------------------------------
// Kernel B: wfold[i] = exp(log_w[i]) * winv[cols[i]]  +  row_start via
// sorted-COO scan (no binary search). 4 nnz per thread, fully coalesced.
// ---------------------------------------------------------------------------
__global__ __launch_bounds__(256) void fold_scan_kernel(
    const float* __restrict__ log_w, const int* __restrict__ cols,
    const float* __restrict__ winv, const int* __restrict__ rows,
    float* __restrict__ wfold, int* __restrict__ row_start) {
    const int i = (blockIdx.x * 256 + threadIdx.x) * 4;
    const float4 lw = *(const float4*)&log_w[i];
    const int4   cc = *(const int4*)&cols[i];
    float4 o;
    o.x = expf(lw.x) * winv[cc.x];
    o.y = expf(lw.y) * winv[cc.y];
    o.z = expf(lw.z) * winv[cc.z];
    o.w = expf(lw.w) * winv[cc.w];
    *(float4*)&wfold[i] = o;

    const int4 rv = *(const int4*)&rows[i];
    const int rj[4] = {rv.x, rv.y, rv.z, rv.w};
    int prev = (i == 0) ? -1 : rows[i - 1];
#pragma unroll
    for (int j = 0; j < 4; ++j) {
        const int cur = rj[j];
        if (cur != prev)
            for (int q = prev + 1; q <= cur; ++q) row_start[q] = i + j;
        prev = cur;
    }
    if (i + 3 == NNZ_TOTAL - 1)
        for (int q = rj[3] + 1; q <= N_NODES; ++q) row_start[q] = NNZ_TOTAL;
}

// ---------------------------------------------------------------------------
// Kernel C: logzv[r] = log(sum exp(log_w[row segment])). 16 lanes/row,
// contiguous coalesced segment reads.
// ---------------------------------------------------------------------------
__global__ __launch_bounds__(256) void logz_kernel(
    const float* __restrict__ log_w, const int* __restrict__ row_start,
    float* __restrict__ logzv) {
    const int t = threadIdx.x;
    const int g = t >> 4, j = t & 15;
    const int r = blockIdx.x * 16 + g;
    const int s = row_start[r], e = row_start[r + 1];
    float sum = 0.f;
    for (int i = s + j; i < e; i += 16) sum += expf(log_w[i]);
    sum += __shfl_xor(sum, 1, 64);
    sum += __shfl_xor(sum, 2, 64);
    sum += __shfl_xor(sum, 4, 64);
    sum += __shfl_xor(sum, 8, 64);
    if (j == 0) logzv[r] = logf(sum);
}

// ---------------------------------------------------------------------------
// Kernel D: per-row sum, TWO rows per wave (rA, rB = rA + 16384).
// Meta: lanes 0-31 load row-A tile cols/wfold, lanes 32-63 row-B.
// 8 dwordx4 gathers (8 nnz each) in flight per wave; bpermute meta
// redistribution; shfl fold epilogue; precomputed logz.
// ---------------------------------------------------------------------------
__global__ __launch_bounds__(256, 4) void sum_rows_kernel(
    const unsigned char* __restrict__ ex8, const float* __restrict__ wfold,
    const int* __restrict__ cols, const int* __restrict__ row_start,
    const float* __restrict__ logzv, float* __restrict__ out) {
    const int wave = threadIdx.x >> 6;   // 0..3
    const int lane = threadIdx.x & 63;
    const int bid  = blockIdx.x;         // grid = 4096, %8==0
    const int pb   = (bid & 7) * 512 + (bid >> 3);   // XCD swizzle
    const int pid  = pb * 4 + wave;                  // 0..16383
    const int rA   = pid;
    const int rB   = pid + N_NODES / 2;

    const int sA = row_start[rA], eA = row_start[rA + 1];
    const int sB = row_start[rB], eB = row_start[rB + 1];
    const int slot = lane >> 3;                  // nnz slot within granule
    const int sub  = lane & 7;                   // 16B chunk within 128B row
    const unsigned boff = (unsigned)sub * 16u;
    const int half  = lane >> 5;                 // 0: meta A, 1: meta B
    const int mlane = lane & 31;

    float accA[16], accB[16];
#pragma unroll
    for (int k = 0; k < 16; ++k) { accA[k] = 0.f; accB[k] = 0.f; }

    int baseA = sA, baseB = sB;
    while (baseA < eA || baseB < eB) {
        // meta for both rows in one pair of coalesced loads
        const int  mbase = half ? baseB : baseA;
        const int  mend  = half ? eB : eA;
        const int  mi    = mbase + mlane;
        const bool mv    = mi < mend;
        const int   cm = __builtin_nontemporal_load(&cols[mv ? mi : 0]);
        const float wm = mv ? __builtin_nontemporal_load(&wfold[mi]) : 0.f;

        const int segA = eA - baseA;   // wave-uniform
        const int segB = eB - baseB;

        int ct[8]; float wt[8]; uint4 g[8];

        // Phase A: redistribute meta (granules 0-3: row A, 4-7: row B)
#pragma unroll
        for (int t8 = 0; t8 < 4; ++t8) {
            if (t8 * 8 < segA) {
                const int pa = (t8 * 8 + slot) * 4;
                ct[t8] = __builtin_amdgcn_ds_bpermute(pa, cm);
                wt[t8] = __uint_as_float(__builtin_amdgcn_ds_bpermute(
                    pa, __float_as_uint(wm)));
            }
        }
#pragma unroll
        for (int t8 = 0; t8 < 4; ++t8) {
            if (t8 * 8 < segB) {
                const int pa = (32 + t8 * 8 + slot) * 4;
                ct[4 + t8] = __builtin_amdgcn_ds_bpermute(pa, cm);
                wt[4 + t8] = __uint_as_float(__builtin_amdgcn_ds_bpermute(
                    pa, __float_as_uint(wm)));
            }
        }
        // Phase B: issue all gathers (up to 8 dwordx4 in flight)
#pragma unroll
        for (int t8 = 0; t8 < 4; ++t8) {
            if (t8 * 8 < segA)
                g[t8] = *(const uint4*)(ex8 +
                        ((size_t)(unsigned)ct[t8] << 7) + boff);
        }
#pragma unroll
        for (int t8 = 0; t8 < 4; ++t8) {
            if (t8 * 8 < segB)
                g[4 + t8] = *(const uint4*)(ex8 +
                        ((size_t)(unsigned)ct[4 + t8] << 7) + boff);
        }
        // Phase C: consume
#pragma unroll
        for (int t8 = 0; t8 < 4; ++t8) {
            if (t8 * 8 < segA) {
                const float wtv = wt[t8];
                const unsigned* gu = (const unsigned*)&g[t8];
#pragma unroll
                for (int q = 0; q < 4; ++q) {
                    const fx2 lo = __builtin_amdgcn_cvt_pk_f32_fp8((int)gu[q], false);
                    const fx2 hi = __builtin_amdgcn_cvt_pk_f32_fp8((int)gu[q], true);
                    accA[q * 4 + 0] = fmaf(wtv, lo.x, accA[q * 4 + 0]);
                    accA[q * 4 + 1] = fmaf(wtv, lo.y, accA[q * 4 + 1]);
                    accA[q * 4 + 2] = fmaf(wtv, hi.x, accA[q * 4 + 2]);
                    accA[q * 4 + 3] = fmaf(wtv, hi.y, accA[q * 4 + 3]);
                }
            }
        }
#pragma unroll
        for (int t8 = 0; t8 < 4; ++t8) {
            if (t8 * 8 < segB) {
                const float wtv = wt[4 + t8];
                const unsigned* gu = (const unsigned*)&g[4 + t8];
#pragma unroll
                for (int q = 0; q < 4; ++q) {
                    const fx2 lo = __builtin_amdgcn_cvt_pk_f32_fp8((int)gu[q], false);
                    const fx2 hi = __builtin_amdgcn_cvt_pk_f32_fp8((int)gu[q], true);
                    accB[q * 4 + 0] = fmaf(wtv, lo.x, accB[q * 4 + 0]);
                    accB[q * 4 + 1] = fmaf(wtv, lo.y, accB[q * 4 + 1]);
                    accB[q * 4 + 2] = fmaf(wtv, hi.x, accB[q * 4 + 2]);
                    accB[q * 4 + 3] = fmaf(wtv, hi.y, accB[q * 4 + 3]);
                }
            }
        }
        baseA += 32; baseB += 32;
    }

    // fold the 8 slot-groups
#pragma unroll
    for (int k = 0; k < 16; ++k) {
        accA[k] += __shfl_xor(accA[k], 8, 64);
        accA[k] += __shfl_xor(accA[k], 16, 64);
        accA[k] += __shfl_xor(accA[k], 32, 64);
        accB[k] += __shfl_xor(accB[k], 8, 64);
        accB[k] += __shfl_xor(accB[k], 16, 64);
        accB[k] += __shfl_xor(accB[k], 32, 64);
    }

    if (lane < 8) {
        const float lzA = logzv[rA];
        const float lzB = logzv[rB];
        const int b0 = lane * 16;
#pragma unroll
        for (int k = 0; k < 16; ++k) {
            out[(size_t)(b0 + k) * N_NODES + rA] = logf(accA[k]) - lzA;
            out[(size_t)(b0 + k) * N_NODES + rB] = logf(accB[k]) - lzB;
        }
    }
}

// ---------------------------------------------------------------------------
extern "C" void kernel_launch(void* const* d_in, const int* in_sizes, int n_in,
                              void* d_out, int out_size, void* d_ws, size_t ws_size,
                              hipStream_t stream) {
    const float* child_ll = (const float*)d_in[0];
    const float* log_w    = (const float*)d_in[1];
    const int*   rows     = (const int*)d_in[2];
    const int*   cols     = (const int*)d_in[3];
    float*       out      = (float*)d_out;

    unsigned char* ex8 = (unsigned char*)d_ws;                             // 8.4 MB
    float* winv      = (float*)((char*)d_ws + (size_t)N_CHILD * 128);      // 256 KB
    float* wfold     = (float*)((char*)winv + (size_t)N_CHILD * 4);        // 4 MB
    int*   row_start = (int*)((char*)wfold + (size_t)NNZ_TOTAL * 4);       // 128 KB
    float* logzv     = (float*)((char*)row_start + (size_t)(N_NODES + 1) * 4);

    exp8_kernel<<<N_CHILD / 64, 256, 0, stream>>>(child_ll, ex8, winv);
    fold_scan_kernel<<<NNZ_TOTAL / 1024, 256, 0, stream>>>(
        log_w, cols, winv, rows, wfold, row_start);
    logz_kernel<<<N_NODES / 16, 256, 0, stream>>>(log_w, row_start, logzv);
    sum_rows_kernel<<<N_NODES / 8, 256, 0, stream>>>(ex8, wfold, cols,
                                                     row_start, logzv, out);
}